// Round 9
// baseline (440.294 us; speedup 1.0000x reference)
//
#include <hip/hip_runtime.h>
#include <hip/hip_bf16.h>

#define BB 2
#define SS 2048
#define DDIM 1024
#define HH 16
#define DHH 64
#define DFF_ 4096
#define BS 4096   // B*S
#define NQKV 3072 // Q|K|V concatenated feature dim

typedef unsigned short u16;
using short8  = __attribute__((ext_vector_type(8))) short;
using floatx4 = __attribute__((ext_vector_type(4))) float;

__device__ __forceinline__ u16 f2b(float f){
  union { unsigned int u; float f; } v; v.f = f;
  unsigned int u = v.u;
  u += 0x7FFFu + ((u >> 16) & 1u);   // RNE
  return (u16)(u >> 16);
}

__device__ __forceinline__ void gl2lds16(const u16* g, u16* l){
  __builtin_amdgcn_global_load_lds((const __attribute__((address_space(1))) void*)g,
                                   (__attribute__((address_space(3))) void*)l, 16, 0, 0);
}

// ---------------- transpose+cast tile helper: out_bf16[c][r] = in_f32[r][c] ----------------
__device__ __forceinline__ void tcast(const float* __restrict__ in, u16* __restrict__ out,
                                      int R, int C, int tile, float (*sh)[33]){
  int nr = R >> 5;
  int tr = tile % nr, tc = tile / nr;
  int r0 = tr * 32, c0 = tc * 32;
  int tx = threadIdx.x & 31, ty = threadIdx.x >> 5;   // ty 0..7
  for (int i = ty; i < 32; i += 8)
    sh[i][tx] = in[(size_t)(r0 + i) * C + c0 + tx];
  __syncthreads();
  for (int i = ty; i < 32; i += 8)
    out[(size_t)(c0 + i) * R + r0 + tx] = f2b(sh[tx][i]);
}

// ---------------- fused prep: Wq/Wk/Wv/W0/W1 transposes + bias concat, 1 launch ----------------
__global__ __launch_bounds__(256) void prep_k(
    const float* __restrict__ Wq, const float* __restrict__ Wk, const float* __restrict__ Wv,
    const float* __restrict__ W0, const float* __restrict__ W1,
    const float* __restrict__ bq, const float* __restrict__ bk, const float* __restrict__ bv,
    u16* __restrict__ wqkvT, u16* __restrict__ w0T, u16* __restrict__ w1T,
    float* __restrict__ biasQKV)
{
  __shared__ float sh[32][33];
  int id = blockIdx.x;
  if (id < 3072){
    int which = id >> 10, lid = id & 1023;
    const float* src = which == 0 ? Wq : (which == 1 ? Wk : Wv);
    u16* dst = wqkvT + (size_t)which * 1048576;
    int bat = lid >> 6, t = lid & 63;              // 64 tiles per [1024][64] head
    tcast(src + (size_t)bat * 65536, dst + (size_t)bat * 65536, 1024, 64, t, sh);
  } else if (id < 4096){
    tcast(W0, w0T, 1024, 1024, id - 3072, sh);
  } else if (id < 8192){
    tcast(W1, w1T, 1024, 4096, id - 4096, sh);
  } else {
    int idx = (id - 8192) * 256 + threadIdx.x;
    if (idx < 3072){
      float v = idx < 1024 ? bq[idx] : (idx < 2048 ? bk[idx - 1024] : bv[idx - 2048]);
      biasQKV[idx] = v;
    }
  }
}

// ---------------- standalone transpose (W2, launched late for ws aliasing) ----------------
__global__ __launch_bounds__(256) void transpose_cast_k(const float* __restrict__ in,
                                                        u16* __restrict__ out, int R, int C){
  __shared__ float sh[32][33];
  int nrC = C >> 5;
  int tile = blockIdx.x;
  int tr = tile / nrC, tc = tile % nrC;
  int r0 = tr * 32, c0 = tc * 32;
  int tx = threadIdx.x & 31, ty = threadIdx.x >> 5;
  for (int i = ty; i < 32; i += 8)
    sh[i][tx] = in[(size_t)(r0 + i) * C + c0 + tx];
  __syncthreads();
  for (int i = ty; i < 32; i += 8)
    out[(size_t)(c0 + i) * R + r0 + tx] = f2b(sh[tx][i]);
}

// ---------------- V-transpose: VT[bh][dh][s] = QKV[b*S+s][2048 + h*64 + dh] ----------------
__global__ __launch_bounds__(256) void vt_k(const u16* __restrict__ QKV, u16* __restrict__ VT){
  __shared__ u16 t[32][33];
  int bh = blockIdx.z; int b = bh >> 4, h = bh & 15;
  int s0 = blockIdx.x * 32, d0 = blockIdx.y * 32;
  int tx = threadIdx.x & 31, ty = threadIdx.x >> 5;
  const u16* src = QKV + (size_t)b * SS * NQKV + 2048 + h * DHH;
  for (int i = ty; i < 32; i += 8)
    t[i][tx] = src[(size_t)(s0 + i) * NQKV + d0 + tx];
  __syncthreads();
  u16* dst = VT + (size_t)bh * DHH * SS;
  for (int i = ty; i < 32; i += 8)
    dst[(size_t)(d0 + i) * SS + s0 + tx] = t[tx][i];
}

// ---------------- LayerNorm ----------------
__global__ __launch_bounds__(256) void ln_k(const float* __restrict__ x,
                                            const float* __restrict__ gamma,
                                            const float* __restrict__ beta,
                                            u16* __restrict__ y){
  int row = blockIdx.x;
  const float4* xr = (const float4*)(x + (size_t)row * DDIM);
  int tid = threadIdx.x;
  float4 v = xr[tid];
  float s  = v.x + v.y + v.z + v.w;
  float ss = v.x*v.x + v.y*v.y + v.z*v.z + v.w*v.w;
  for (int o = 1; o < 64; o <<= 1){ s += __shfl_xor(s, o, 64); ss += __shfl_xor(ss, o, 64); }
  __shared__ float smem[8];
  int wid = tid >> 6;
  if ((tid & 63) == 0){ smem[wid] = s; smem[wid + 4] = ss; }
  __syncthreads();
  s  = smem[0] + smem[1] + smem[2] + smem[3];
  ss = smem[4] + smem[5] + smem[6] + smem[7];
  float mu  = s / (float)DDIM;
  float var = ss / (float)DDIM - mu * mu;
  float rs  = rsqrtf(var + 1e-5f);
  const float4* gp = (const float4*)gamma;
  const float4* bp = (const float4*)beta;
  float4 g = gp[tid], b = bp[tid];
  u16* yr = y + (size_t)row * DDIM + tid*4;
  yr[0] = f2b((v.x - mu) * rs * g.x + b.x);
  yr[1] = f2b((v.y - mu) * rs * g.y + b.y);
  yr[2] = f2b((v.z - mu) * rs * g.z + b.z);
  yr[3] = f2b((v.w - mu) * rs * g.w + b.w);
}

// ---------------- MFMA GEMM, BK=64 as two BK=32 planes ----------------
template<int TM, int TN>
__global__ __launch_bounds__(256) void gemm_k(
    const u16* __restrict__ A, const u16* __restrict__ Bt,
    const float* __restrict__ bias, const float* __restrict__ res,
    void* __restrict__ Cv, int M, int N, int K, int relu, int writeBf16)
{
  constexpr int ACH = TM / 16;
  constexpr int BCH = TN / 16;
  constexpr int CH1 = ACH + BCH;
  constexpr int CPW = (2 * CH1) / 4;
  constexpr int MI  = TM / 32;
  constexpr int NI  = TN / 32;

  __shared__ __align__(16) u16 As[2][TM * 32];
  __shared__ __align__(16) u16 Bs[2][TN * 32];

  int tid  = threadIdx.x;
  int wave = tid >> 6, lane = tid & 63;
  int quad = lane >> 4, l16 = lane & 15;

  int gx = gridDim.x, gy = gridDim.y;
  int bid = blockIdx.x + gx * blockIdx.y;
  int xcd = bid & 7, idx = bid >> 3;
  int by  = xcd * (gy >> 3) + idx / gx;
  int bx  = idx % gx;

  int m0 = by * TM, n0 = bx * TN;
  int wm = (wave >> 1) * (TM / 2), wn = (wave & 1) * (TN / 2);

  floatx4 acc[MI][NI] = {};

  int srow = lane >> 2;
  int scol = (lane & 3) * 8;
  const u16* gptr[CPW]; u16* lptr[CPW];
#pragma unroll
  for (int k = 0; k < CPW; k++){
    int c = wave * CPW + k;
    int p = c / CH1, cc = c % CH1;
    if (cc < ACH){
      gptr[k] = A  + (size_t)(m0 + cc*16 + srow) * K + p*32 + scol;
      lptr[k] = &As[p][cc * 512];
    } else {
      gptr[k] = Bt + (size_t)(n0 + (cc-ACH)*16 + srow) * K + p*32 + scol;
      lptr[k] = &Bs[p][(cc-ACH) * 512];
    }
  }

  for (int kt = 0; kt < K; kt += 64){
#pragma unroll
    for (int k = 0; k < CPW; k++){ gl2lds16(gptr[k], lptr[k]); gptr[k] += 64; }
    __syncthreads();
#pragma unroll
    for (int p = 0; p < 2; p++){
      short8 af[MI], bf[NI];
#pragma unroll
      for (int i = 0; i < MI; i++)
        af[i] = *(short8*)&As[p][(wm + i*16 + l16)*32 + quad*8];
#pragma unroll
      for (int j = 0; j < NI; j++)
        bf[j] = *(short8*)&Bs[p][(wn + j*16 + l16)*32 + quad*8];
#pragma unroll
      for (int i = 0; i < MI; i++)
#pragma unroll
        for (int j = 0; j < NI; j++)
          acc[i][j] = __builtin_amdgcn_mfma_f32_16x16x32_bf16(af[i], bf[j], acc[i][j], 0,0,0);
    }
    __syncthreads();
  }

  u16*   Cb = (u16*)Cv;
  float* Cf = (float*)Cv;
#pragma unroll
  for (int j = 0; j < NI; j++){
    int col = n0 + wn + j*16 + l16;
    float bj = bias ? bias[col] : 0.f;
#pragma unroll
    for (int i = 0; i < MI; i++){
#pragma unroll
      for (int r = 0; r < 4; r++){
        int row = m0 + wm + i*16 + quad*4 + r;
        float v = acc[i][j][r] + bj;
        if (relu) v = v > 0.f ? v : 0.f;
        if (res)  v += res[(size_t)row * N + col];
        if (writeBf16) Cb[(size_t)row * N + col] = f2b(v);
        else           Cf[(size_t)row * N + col] = v;
      }
    }
  }
}

// ---------------- causal flash attention, Q-tile=128, K-tile=128, max-free softmax ----------------
// Each wave handles 2 sequential 16-row q-frags (f=0,1), reusing its private Ps buffer.
// Diagonal-tile skips: st-group fully masked iff st > wave+4f; PV c-group iff c > (wave+4f)>>1.
#define KT   128
#define KsLD 72    // 64 + 8 pad
#define VTLD 136   // 128 + 8 pad
#define PsLD 136

__global__ __launch_bounds__(256) void attn_k(
    const u16* __restrict__ QKV, const u16* __restrict__ VT, u16* __restrict__ O)
{
  int bh = blockIdx.x;                       // 0..31
  int b = bh >> 4, h = bh & 15;
  int qt = (int)gridDim.y - 1 - blockIdx.y;  // LPT: heaviest q-tiles first
  int q0 = qt * 128;
  const u16* Qb_  = QKV + (size_t)b * SS * NQKV + h * DHH;
  const u16* Kb_  = Qb_ + 1024;
  const u16* VTb_ = VT + (size_t)bh * DHH * SS;

  __shared__ __align__(16) u16 Ks [KT * KsLD];     // [s][dh]
  __shared__ __align__(16) u16 VTs[DHH * VTLD];    // [dh][s]
  __shared__ __align__(16) u16 Ps [4][16 * PsLD];  // per-wave [q][s], reused across f

  int tid = threadIdx.x;
  int wave = tid >> 6, lane = tid & 63;
  int quad = lane >> 4, l16 = lane & 15;

  short8 qf[2][2];
#pragma unroll
  for (int f = 0; f < 2; f++){
    const u16* qp = Qb_ + (size_t)(q0 + f*64 + wave*16 + l16) * NQKV + quad*8;
    qf[f][0] = *(const short8*)qp;
    qf[f][1] = *(const short8*)(qp + 32);
  }

  float l_acc[2][4] = {};
  floatx4 oacc[2][4] = {};

  int nk = qt + 1;
  const float qs = 0.125f * 1.44269504088896f;   // scale * log2(e)

  for (int kt = 0; kt < nk; kt++){
    int k0 = kt * KT;
    __syncthreads();
#pragma unroll
    for (int it = 0; it < 4; it++){
      int g = tid + it * 256;
      {
        int row = g >> 3, c = (g & 7) * 8;
        *(short8*)&Ks[row * KsLD + c] = *(const short8*)(Kb_ + (size_t)(k0 + row) * NQKV + c);
      }
      {
        int dh = g >> 4, c = (g & 15) * 8;
        *(short8*)&VTs[dh * VTLD + c] = *(const short8*)(VTb_ + (size_t)dh * SS + k0 + c);
      }
    }
    __syncthreads();

    bool last = (kt == nk - 1);
#pragma unroll
    for (int f = 0; f < 2; f++){
      int lim = wave + 4*f;                 // on last tile: st>lim fully masked
      int stmax = last ? lim : 7;
      floatx4 sacc[8] = {};
#pragma unroll
      for (int st = 0; st < 8; st++){
        if (st <= stmax){
          short8 kb0 = *(short8*)&Ks[(st*16 + l16) * KsLD + quad*8];
          short8 kb1 = *(short8*)&Ks[(st*16 + l16) * KsLD + 32 + quad*8];
          sacc[st] = __builtin_amdgcn_mfma_f32_16x16x32_bf16(qf[f][0], kb0, sacc[st], 0,0,0);
          sacc[st] = __builtin_amdgcn_mfma_f32_16x16x32_bf16(qf[f][1], kb1, sacc[st], 0,0,0);
        }
      }
      int qrow = q0 + f*64 + wave*16;
#pragma unroll
      for (int st = 0; st < 8; st++){
        if (st <= stmax){
          if (last){
            int col = k0 + st*16 + l16;
#pragma unroll
            for (int r = 0; r < 4; r++){
              float e = exp2f(sacc[st][r] * qs);
              e = (col <= qrow + quad*4 + r) ? e : 0.f;
              l_acc[f][r] += e;
              Ps[wave][(quad*4 + r) * PsLD + st*16 + l16] = f2b(e);
            }
          } else {
#pragma unroll
            for (int r = 0; r < 4; r++){
              float e = exp2f(sacc[st][r] * qs);
              l_acc[f][r] += e;
              Ps[wave][(quad*4 + r) * PsLD + st*16 + l16] = f2b(e);
            }
          }
        } else {
#pragma unroll
          for (int r = 0; r < 4; r++)
            Ps[wave][(quad*4 + r) * PsLD + st*16 + l16] = 0;
        }
      }
      asm volatile("s_waitcnt lgkmcnt(0)" ::: "memory");   // per-wave Ps write->read

      int cmax = last ? (lim >> 1) : 3;
      short8 pa[4];
#pragma unroll
      for (int c = 0; c < 4; c++)
        pa[c] = *(short8*)&Ps[wave][l16 * PsLD + c*32 + quad*8];
#pragma unroll
      for (int ost = 0; ost < 4; ost++){
#pragma unroll
        for (int c = 0; c < 4; c++){
          if (c <= cmax){
            short8 vb = *(short8*)&VTs[(ost*16 + l16) * VTLD + c*32 + quad*8];
            oacc[f][ost] = __builtin_amdgcn_mfma_f32_16x16x32_bf16(pa[c], vb, oacc[f][ost], 0,0,0);
          }
        }
      }
    }
  }

#pragma unroll
  for (int f = 0; f < 2; f++){
#pragma unroll
    for (int r = 0; r < 4; r++){
      for (int o = 1; o < 16; o <<= 1) l_acc[f][r] += __shfl_xor(l_acc[f][r], o, 64);
    }
    float inv[4];
#pragma unroll
    for (int r = 0; r < 4; r++) inv[r] = 1.0f / l_acc[f][r];
#pragma unroll
    for (int ost = 0; ost < 4; ost++)
#pragma unroll
      for (int r = 0; r < 4; r++){
        int s  = q0 + f*64 + wave*16 + quad*4 + r;
        int dh = ost*16 + l16;
        O[((size_t)b * SS + s) * DDIM + h * DHH + dh] = f2b(oacc[f][ost][r] * inv[r]);
      }
  }
}

// ---------------- launch ----------------
extern "C" void kernel_launch(void* const* d_in, const int* in_sizes, int n_in,
                              void* d_out, int out_size, void* d_ws, size_t ws_size,
                              hipStream_t stream) {
  const float* X   = (const float*)d_in[0];
  const float* g1  = (const float*)d_in[2];
  const float* be1 = (const float*)d_in[3];
  const float* Wq  = (const float*)d_in[4];
  const float* bq  = (const float*)d_in[5];
  const float* Wk  = (const float*)d_in[6];
  const float* bk  = (const float*)d_in[7];
  const float* Wv  = (const float*)d_in[8];
  const float* bv  = (const float*)d_in[9];
  const float* W0  = (const float*)d_in[10];
  const float* b0  = (const float*)d_in[11];
  const float* g2  = (const float*)d_in[12];
  const float* be2 = (const float*)d_in[13];
  const float* W1  = (const float*)d_in[14];
  const float* b1  = (const float*)d_in[15];
  const float* W2  = (const float*)d_in[16];
  const float* b2  = (const float*)d_in[17];
  float* out = (float*)d_out;   // holds X1 (f32) after W0, final output after FFN2

  u16* ws16 = (u16*)d_ws;
  u16* wqkvT = ws16;                         // 3,145,728  [3072][1024]
  u16* w0T   = ws16 + 3145728;               // 1,048,576  [1024][1024]
  u16* w2T   = ws16;                         // aliases region0 (dead after QKV+W0 gemms)
  u16* w1T   = ws16 + 4194304;               // 4,194,304  [4096][1024]
  u16* QKVb  = ws16 + 8388608;               // 12,582,912 [4096][3072]
  u16* VTb   = ws16 + 8388608 + 12582912;    // 4,194,304  [32][64][2048]
  u16* hb    = ws16 + 8388608;               // aliases QKV+VT [4096][4096]
  u16* Xn    = ws16 + 25165824;              // 4,194,304 (Xn -> attnB -> Xn2)
  u16* attnB = Xn;
  float* biasQKV = (float*)(ws16 + 29360128);  // 3072 f32

  prep_k<<<dim3(8204), 256, 0, stream>>>(Wq, Wk, Wv, W0, W1, bq, bk, bv,
                                         wqkvT, w0T, w1T, biasQKV);

  ln_k<<<dim3(BS), 256, 0, stream>>>(X, g1, be1, Xn);

  // fused QKV projection: 768 blocks (3/CU)
  gemm_k<128,128><<<dim3(24, 32), 256, 0, stream>>>(Xn, wqkvT, biasQKV, nullptr, QKVb,
      BS, NQKV, 1024, 0, 1);

  vt_k<<<dim3(64, 2, 32), 256, 0, stream>>>(QKVb, VTb);

  // attention: Q-tile 128 -> 512 blocks
  attn_k<<<dim3(32, 16), 256, 0, stream>>>(QKVb, VTb, attnB);

  // W0 projection + residual(X) -> X1 f32 in d_out. 512 blocks (2/CU)
  gemm_k<64,128><<<dim3(8, 64), 256, 0, stream>>>(attnB, w0T, b0, X, out,
      BS, DDIM, 1024, 0, 0);

  transpose_cast_k<<<dim3(4096), 256, 0, stream>>>(W2, w2T, 4096, 1024);

  ln_k<<<dim3(BS), 256, 0, stream>>>(out, g2, be2, Xn);   // Xn2 (attnB dead)

  // FFN1: 128x128, 1024 blocks (4/CU)
  gemm_k<128,128><<<dim3(32, 32), 256, 0, stream>>>(Xn, w1T, b1, nullptr, hb,
      BS, DFF_, 1024, 1, 1);
  // FFN2: TM=64, in-place residual accumulate into d_out (X1)
  gemm_k<64,128><<<dim3(8, 64), 256, 0, stream>>>(hb, w2T, b2, out, out,
      BS, DDIM, DFF_, 0, 0);
}

// Round 10
// 421.448 us; speedup vs baseline: 1.0447x; 1.0447x over previous
//
#include <hip/hip_runtime.h>
#include <hip/hip_bf16.h>

#define BB 2
#define SS 2048
#define DDIM 1024
#define HH 16
#define DHH 64
#define DFF_ 4096
#define BS 4096   // B*S
#define NQKV 3072 // Q|K|V concatenated feature dim

typedef unsigned short u16;
using short8  = __attribute__((ext_vector_type(8))) short;
using floatx4 = __attribute__((ext_vector_type(4))) float;

__device__ __forceinline__ u16 f2b(float f){
  union { unsigned int u; float f; } v; v.f = f;
  unsigned int u = v.u;
  u += 0x7FFFu + ((u >> 16) & 1u);   // RNE
  return (u16)(u >> 16);
}

__device__ __forceinline__ void gl2lds16(const u16* g, u16* l){
  __builtin_amdgcn_global_load_lds((const __attribute__((address_space(1))) void*)g,
                                   (__attribute__((address_space(3))) void*)l, 16, 0, 0);
}

// ---------------- LayerNorm row (device): y_bf16 = (x-mu)*rsqrt(var+eps)*gamma + beta ----------------
__device__ __forceinline__ void ln_row(const float* __restrict__ x,
                                       const float* __restrict__ gamma,
                                       const float* __restrict__ beta,
                                       u16* __restrict__ y, int row, float* smem){
  const float4* xr = (const float4*)(x + (size_t)row * DDIM);
  int tid = threadIdx.x;
  float4 v = xr[tid];
  float s  = v.x + v.y + v.z + v.w;
  float ss = v.x*v.x + v.y*v.y + v.z*v.z + v.w*v.w;
  for (int o = 1; o < 64; o <<= 1){ s += __shfl_xor(s, o, 64); ss += __shfl_xor(ss, o, 64); }
  int wid = tid >> 6;
  if ((tid & 63) == 0){ smem[wid] = s; smem[wid + 4] = ss; }
  __syncthreads();
  s  = smem[0] + smem[1] + smem[2] + smem[3];
  ss = smem[4] + smem[5] + smem[6] + smem[7];
  float mu  = s / (float)DDIM;
  float var = ss / (float)DDIM - mu * mu;
  float rs  = rsqrtf(var + 1e-5f);
  const float4* gp = (const float4*)gamma;
  const float4* bp = (const float4*)beta;
  float4 g = gp[tid], b = bp[tid];
  u16* yr = y + (size_t)row * DDIM + tid*4;
  yr[0] = f2b((v.x - mu) * rs * g.x + b.x);
  yr[1] = f2b((v.y - mu) * rs * g.y + b.y);
  yr[2] = f2b((v.z - mu) * rs * g.z + b.z);
  yr[3] = f2b((v.w - mu) * rs * g.w + b.w);
}

// ---------------- transpose+cast tile helper: out_bf16[c][r] = in_f32[r][c] ----------------
__device__ __forceinline__ void tcast(const float* __restrict__ in, u16* __restrict__ out,
                                      int R, int C, int tile, float (*sh)[33]){
  int nr = R >> 5;
  int tr = tile % nr, tc = tile / nr;
  int r0 = tr * 32, c0 = tc * 32;
  int tx = threadIdx.x & 31, ty = threadIdx.x >> 5;   // ty 0..7
  for (int i = ty; i < 32; i += 8)
    sh[i][tx] = in[(size_t)(r0 + i) * C + c0 + tx];
  __syncthreads();
  for (int i = ty; i < 32; i += 8)
    out[(size_t)(c0 + i) * R + r0 + tx] = f2b(sh[tx][i]);
}

// ---------------- fused: LN1 + Wq/Wk/Wv/W0/W1 transposes + bias concat, 1 launch ----------------
// blocks: [0,4096) LN1 rows; [4096,7168) Wq|Wk|Wv; [7168,8192) W0; [8192,12288) W1; [12288,12300) bias
__global__ __launch_bounds__(256) void prep_ln1_k(
    const float* __restrict__ X, const float* __restrict__ g1, const float* __restrict__ be1,
    u16* __restrict__ Xn,
    const float* __restrict__ Wq, const float* __restrict__ Wk, const float* __restrict__ Wv,
    const float* __restrict__ W0, const float* __restrict__ W1,
    const float* __restrict__ bq, const float* __restrict__ bk, const float* __restrict__ bv,
    u16* __restrict__ wqkvT, u16* __restrict__ w0T, u16* __restrict__ w1T,
    float* __restrict__ biasQKV)
{
  __shared__ float sh[32][33];
  __shared__ float smem8[8];
  int id = blockIdx.x;
  if (id < 4096){
    ln_row(X, g1, be1, Xn, id, smem8);
  } else if (id < 7168){
    int lid2 = id - 4096;
    int which = lid2 >> 10, lid = lid2 & 1023;
    const float* src = which == 0 ? Wq : (which == 1 ? Wk : Wv);
    u16* dst = wqkvT + (size_t)which * 1048576;
    int bat = lid >> 6, t = lid & 63;              // 64 tiles per [1024][64] head
    tcast(src + (size_t)bat * 65536, dst + (size_t)bat * 65536, 1024, 64, t, sh);
  } else if (id < 8192){
    tcast(W0, w0T, 1024, 1024, id - 7168, sh);
  } else if (id < 12288){
    tcast(W1, w1T, 1024, 4096, id - 8192, sh);
  } else {
    int idx = (id - 12288) * 256 + threadIdx.x;
    if (idx < 3072){
      float v = idx < 1024 ? bq[idx] : (idx < 2048 ? bk[idx - 1024] : bv[idx - 2048]);
      biasQKV[idx] = v;
    }
  }
}

// ---------------- fused: LN2 + W2 transpose, 1 launch ----------------
// blocks: [0,4096) LN2 rows on X1; [4096,8192) W2 tiles ([4096][1024] -> w2T)
__global__ __launch_bounds__(256) void w2t_ln2_k(
    const float* __restrict__ X1, const float* __restrict__ g2, const float* __restrict__ be2,
    u16* __restrict__ Xn2, const float* __restrict__ W2, u16* __restrict__ w2T)
{
  __shared__ float sh[32][33];
  __shared__ float smem8[8];
  int id = blockIdx.x;
  if (id < 4096){
    ln_row(X1, g2, be2, Xn2, id, smem8);
  } else {
    int tile = id - 4096;
    int tr = tile / 32, tc = tile % 32;   // R=4096, C=1024
    int r0 = tr * 32, c0 = tc * 32;
    int tx = threadIdx.x & 31, ty = threadIdx.x >> 5;
    for (int i = ty; i < 32; i += 8)
      sh[i][tx] = W2[(size_t)(r0 + i) * 1024 + c0 + tx];
    __syncthreads();
    for (int i = ty; i < 32; i += 8)
      w2T[(size_t)(c0 + i) * 4096 + r0 + tx] = f2b(sh[tx][i]);
  }
}

// ---------------- V-transpose: VT[bh][dh][s] = QKV[b*S+s][2048 + h*64 + dh] ----------------
__global__ __launch_bounds__(256) void vt_k(const u16* __restrict__ QKV, u16* __restrict__ VT){
  __shared__ u16 t[32][33];
  int bh = blockIdx.z; int b = bh >> 4, h = bh & 15;
  int s0 = blockIdx.x * 32, d0 = blockIdx.y * 32;
  int tx = threadIdx.x & 31, ty = threadIdx.x >> 5;
  const u16* src = QKV + (size_t)b * SS * NQKV + 2048 + h * DHH;
  for (int i = ty; i < 32; i += 8)
    t[i][tx] = src[(size_t)(s0 + i) * NQKV + d0 + tx];
  __syncthreads();
  u16* dst = VT + (size_t)bh * DHH * SS;
  for (int i = ty; i < 32; i += 8)
    dst[(size_t)(d0 + i) * SS + s0 + tx] = t[tx][i];
}

// ---------------- MFMA GEMM, BK=64 as two BK=32 planes ----------------
template<int TM, int TN>
__global__ __launch_bounds__(256) void gemm_k(
    const u16* __restrict__ A, const u16* __restrict__ Bt,
    const float* __restrict__ bias, const float* __restrict__ res,
    void* __restrict__ Cv, int M, int N, int K, int relu, int writeBf16)
{
  constexpr int ACH = TM / 16;
  constexpr int BCH = TN / 16;
  constexpr int CH1 = ACH + BCH;
  constexpr int CPW = (2 * CH1) / 4;
  constexpr int MI  = TM / 32;
  constexpr int NI  = TN / 32;

  __shared__ __align__(16) u16 As[2][TM * 32];
  __shared__ __align__(16) u16 Bs[2][TN * 32];

  int tid  = threadIdx.x;
  int wave = tid >> 6, lane = tid & 63;
  int quad = lane >> 4, l16 = lane & 15;

  int gx = gridDim.x, gy = gridDim.y;
  int bid = blockIdx.x + gx * blockIdx.y;
  int xcd = bid & 7, idx = bid >> 3;
  int by  = xcd * (gy >> 3) + idx / gx;
  int bx  = idx % gx;

  int m0 = by * TM, n0 = bx * TN;
  int wm = (wave >> 1) * (TM / 2), wn = (wave & 1) * (TN / 2);

  floatx4 acc[MI][NI] = {};

  int srow = lane >> 2;
  int scol = (lane & 3) * 8;
  const u16* gptr[CPW]; u16* lptr[CPW];
#pragma unroll
  for (int k = 0; k < CPW; k++){
    int c = wave * CPW + k;
    int p = c / CH1, cc = c % CH1;
    if (cc < ACH){
      gptr[k] = A  + (size_t)(m0 + cc*16 + srow) * K + p*32 + scol;
      lptr[k] = &As[p][cc * 512];
    } else {
      gptr[k] = Bt + (size_t)(n0 + (cc-ACH)*16 + srow) * K + p*32 + scol;
      lptr[k] = &Bs[p][(cc-ACH) * 512];
    }
  }

  for (int kt = 0; kt < K; kt += 64){
#pragma unroll
    for (int k = 0; k < CPW; k++){ gl2lds16(gptr[k], lptr[k]); gptr[k] += 64; }
    __syncthreads();
#pragma unroll
    for (int p = 0; p < 2; p++){
      short8 af[MI], bf[NI];
#pragma unroll
      for (int i = 0; i < MI; i++)
        af[i] = *(short8*)&As[p][(wm + i*16 + l16)*32 + quad*8];
#pragma unroll
      for (int j = 0; j < NI; j++)
        bf[j] = *(short8*)&Bs[p][(wn + j*16 + l16)*32 + quad*8];
#pragma unroll
      for (int i = 0; i < MI; i++)
#pragma unroll
        for (int j = 0; j < NI; j++)
          acc[i][j] = __builtin_amdgcn_mfma_f32_16x16x32_bf16(af[i], bf[j], acc[i][j], 0,0,0);
    }
    __syncthreads();
  }

  u16*   Cb = (u16*)Cv;
  float* Cf = (float*)Cv;
#pragma unroll
  for (int j = 0; j < NI; j++){
    int col = n0 + wn + j*16 + l16;
    float bj = bias ? bias[col] : 0.f;
#pragma unroll
    for (int i = 0; i < MI; i++){
#pragma unroll
      for (int r = 0; r < 4; r++){
        int row = m0 + wm + i*16 + quad*4 + r;
        float v = acc[i][j][r] + bj;
        if (relu) v = v > 0.f ? v : 0.f;
        if (res)  v += res[(size_t)row * N + col];
        if (writeBf16) Cb[(size_t)row * N + col] = f2b(v);
        else           Cf[(size_t)row * N + col] = v;
      }
    }
  }
}

// ---------------- causal flash attention, Q-tile=64, K-tile=128, max-free softmax ----------------
// Round-8 proven config + diagonal-tile skips (st-group fully masked iff st > wave+4*(qt&1)).
#define KT   128
#define KsLD 72    // 64 + 8 pad
#define VTLD 136   // 128 + 8 pad
#define PsLD 136

__global__ __launch_bounds__(256) void attn_k(
    const u16* __restrict__ QKV, const u16* __restrict__ VT, u16* __restrict__ O)
{
  int bh = blockIdx.x;                       // 0..31
  int b = bh >> 4, h = bh & 15;
  int qt = (int)gridDim.y - 1 - blockIdx.y;  // LPT: heaviest q-tiles first
  int q0 = qt * 64;
  const u16* Qb_  = QKV + (size_t)b * SS * NQKV + h * DHH;
  const u16* Kb_  = Qb_ + 1024;
  const u16* VTb_ = VT + (size_t)bh * DHH * SS;

  __shared__ __align__(16) u16 Ks [KT * KsLD];     // [s][dh]
  __shared__ __align__(16) u16 VTs[DHH * VTLD];    // [dh][s]
  __shared__ __align__(16) u16 Ps [4][16 * PsLD];  // per-wave [q][s]

  int tid = threadIdx.x;
  int wave = tid >> 6, lane = tid & 63;
  int quad = lane >> 4, l16 = lane & 15;
  int qrow = q0 + wave * 16;

  short8 qf0, qf1;
  {
    const u16* qp = Qb_ + (size_t)(qrow + l16) * NQKV + quad*8;
    qf0 = *(const short8*)qp;
    qf1 = *(const short8*)(qp + 32);
  }

  float l_acc[4] = {0.f, 0.f, 0.f, 0.f};
  floatx4 oacc[4] = {};

  int nk = (qt >> 1) + 1;
  int lim = wave + 4 * (qt & 1);             // diagonal-tile live st bound
  const float qs = 0.125f * 1.44269504088896f;   // scale * log2(e)

  for (int kt = 0; kt < nk; kt++){
    int k0 = kt * KT;
    __syncthreads();
#pragma unroll
    for (int it = 0; it < 4; it++){
      int g = tid + it * 256;
      {
        int row = g >> 3, c = (g & 7) * 8;
        *(short8*)&Ks[row * KsLD + c] = *(const short8*)(Kb_ + (size_t)(k0 + row) * NQKV + c);
      }
      {
        int dh = g >> 4, c = (g & 15) * 8;
        *(short8*)&VTs[dh * VTLD + c] = *(const short8*)(VTb_ + (size_t)dh * SS + k0 + c);
      }
    }
    __syncthreads();

    bool last = (kt == nk - 1);
    int stmax = last ? lim : 7;
    floatx4 sacc[8] = {};
#pragma unroll
    for (int st = 0; st < 8; st++){
      if (st <= stmax){
        short8 kb0 = *(short8*)&Ks[(st*16 + l16) * KsLD + quad*8];
        short8 kb1 = *(short8*)&Ks[(st*16 + l16) * KsLD + 32 + quad*8];
        sacc[st] = __builtin_amdgcn_mfma_f32_16x16x32_bf16(qf0, kb0, sacc[st], 0,0,0);
        sacc[st] = __builtin_amdgcn_mfma_f32_16x16x32_bf16(qf1, kb1, sacc[st], 0,0,0);
      }
    }

#pragma unroll
    for (int st = 0; st < 8; st++){
      if (st <= stmax){
        if (last){
          int col = k0 + st*16 + l16;
#pragma unroll
          for (int r = 0; r < 4; r++){
            float e = exp2f(sacc[st][r] * qs);
            e = (col <= qrow + quad*4 + r) ? e : 0.f;
            l_acc[r] += e;
            Ps[wave][(quad*4 + r) * PsLD + st*16 + l16] = f2b(e);
          }
        } else {
#pragma unroll
          for (int r = 0; r < 4; r++){
            float e = exp2f(sacc[st][r] * qs);
            l_acc[r] += e;
            Ps[wave][(quad*4 + r) * PsLD + st*16 + l16] = f2b(e);
          }
        }
      } else {
#pragma unroll
        for (int r = 0; r < 4; r++)
          Ps[wave][(quad*4 + r) * PsLD + st*16 + l16] = 0;
      }
    }
    asm volatile("s_waitcnt lgkmcnt(0)" ::: "memory");   // per-wave Ps write->read

    int cmax = last ? (lim >> 1) : 3;
    short8 pa[4];
#pragma unroll
    for (int c = 0; c < 4; c++)
      pa[c] = *(short8*)&Ps[wave][l16 * PsLD + c*32 + quad*8];
#pragma unroll
    for (int ost = 0; ost < 4; ost++){
#pragma unroll
      for (int c = 0; c < 4; c++){
        if (c <= cmax){
          short8 vb = *(short8*)&VTs[(ost*16 + l16) * VTLD + c*32 + quad*8];
          oacc[ost] = __builtin_amdgcn_mfma_f32_16x16x32_bf16(pa[c], vb, oacc[ost], 0,0,0);
        }
      }
    }
  }

#pragma unroll
  for (int r = 0; r < 4; r++){
    for (int o = 1; o < 16; o <<= 1) l_acc[r] += __shfl_xor(l_acc[r], o, 64);
  }
  float inv[4];
#pragma unroll
  for (int r = 0; r < 4; r++) inv[r] = 1.0f / l_acc[r];

#pragma unroll
  for (int ost = 0; ost < 4; ost++)
#pragma unroll
    for (int r = 0; r < 4; r++){
      int s  = qrow + quad*4 + r;
      int dh = ost*16 + l16;
      O[((size_t)b * SS + s) * DDIM + h * DHH + dh] = f2b(oacc[ost][r] * inv[r]);
    }
}

// ---------------- launch ----------------
extern "C" void kernel_launch(void* const* d_in, const int* in_sizes, int n_in,
                              void* d_out, int out_size, void* d_ws, size_t ws_size,
                              hipStream_t stream) {
  const float* X   = (const float*)d_in[0];
  const float* g1  = (const float*)d_in[2];
  const float* be1 = (const float*)d_in[3];
  const float* Wq  = (const float*)d_in[4];
  const float* bq  = (const float*)d_in[5];
  const float* Wk  = (const float*)d_in[6];
  const float* bk  = (const float*)d_in[7];
  const float* Wv  = (const float*)d_in[8];
  const float* bv  = (const float*)d_in[9];
  const float* W0  = (const float*)d_in[10];
  const float* b0  = (const float*)d_in[11];
  const float* g2  = (const float*)d_in[12];
  const float* be2 = (const float*)d_in[13];
  const float* W1  = (const float*)d_in[14];
  const float* b1  = (const float*)d_in[15];
  const float* W2  = (const float*)d_in[16];
  const float* b2  = (const float*)d_in[17];
  float* out = (float*)d_out;   // holds X1 (f32) after W0, final output after FFN2

  u16* ws16 = (u16*)d_ws;
  u16* wqkvT = ws16;                         // 3,145,728  [3072][1024]
  u16* w0T   = ws16 + 3145728;               // 1,048,576  [1024][1024]
  u16* w2T   = ws16;                         // aliases region0 (dead after QKV+W0 gemms)
  u16* w1T   = ws16 + 4194304;               // 4,194,304  [4096][1024]
  u16* QKVb  = ws16 + 8388608;               // 12,582,912 [4096][3072]
  u16* VTb   = ws16 + 8388608 + 12582912;    // 4,194,304  [32][64][2048]
  u16* hb    = ws16 + 8388608;               // aliases QKV+VT [4096][4096]
  u16* Xn    = ws16 + 25165824;              // 4,194,304 (Xn -> attnB -> Xn2)
  u16* attnB = Xn;
  float* biasQKV = (float*)(ws16 + 29360128);  // 3072 f32

  // fused LN1 + weight prep (1 launch)
  prep_ln1_k<<<dim3(12300), 256, 0, stream>>>(X, g1, be1, Xn,
      Wq, Wk, Wv, W0, W1, bq, bk, bv, wqkvT, w0T, w1T, biasQKV);

  // fused QKV projection: 768 blocks (3/CU)
  gemm_k<128,128><<<dim3(24, 32), 256, 0, stream>>>(Xn, wqkvT, biasQKV, nullptr, QKVb,
      BS, NQKV, 1024, 0, 1);

  vt_k<<<dim3(64, 2, 32), 256, 0, stream>>>(QKVb, VTb);

  // attention: round-8 config (Q-tile 64, 1024 blocks) + diagonal skips
  attn_k<<<dim3(32, 32), 256, 0, stream>>>(QKVb, VTb, attnB);

  // W0 projection + residual(X) -> X1 f32 in d_out. 512 blocks (2/CU)
  gemm_k<64,128><<<dim3(8, 64), 256, 0, stream>>>(attnB, w0T, b0, X, out,
      BS, DDIM, 1024, 0, 0);

  // fused LN2 + W2 transpose (region0 dead now)
  w2t_ln2_k<<<dim3(8192), 256, 0, stream>>>(out, g2, be2, Xn, W2, w2T);

  // FFN1: 128x128, 1024 blocks (4/CU)
  gemm_k<128,128><<<dim3(32, 32), 256, 0, stream>>>(Xn, w1T, b1, nullptr, hb,
      BS, DFF_, 1024, 1, 1);
  // FFN2: TM=64, in-place residual accumulate into d_out (X1)
  gemm_k<64,128><<<dim3(8, 64), 256, 0, stream>>>(hb, w2T, b2, out, out,
      BS, DDIM, DFF_, 0, 0);
}